// Round 4
// baseline (3371.628 us; speedup 1.0000x reference)
//
#include <hip/hip_runtime.h>

// Residual VQ on MI355X (gfx950).
// z: [8, 32768, 32] f32; codebooks: [10, 512, 32] f32.
// Outputs (flat f32 in d_out): quantized [B,N,D], indices [B,N,Q] (as float),
// commit_loss [Q] (zeros).
//
// R4: per-stage kernels with the codebook resident in VGPRs (8 codewords per
// lane, 512 per wave). Removes the per-candidate L1 broadcast that capped
// R1 (33% VALU) and R3 (latency-exposed). Per point the wave loads only the
// 32-float residual (wave-uniform), computes 8 distances/lane with the
// bit-exact R1 FMA tree, and argmins via a shfl_xor butterfly with
// lower-index tie-break (== numpy first-min). Residual round-trips through
// the quantized region of d_out; the proven replay kernel rebuilds
// quantized bit-exactly from the indices at the end.

#define RVQ_B 8
#define RVQ_N 32768
#define RVQ_D 32
#define RVQ_Q 10
#define RVQ_C 512

static constexpr int  NPTS     = RVQ_B * RVQ_N;             // 262144
static constexpr long IDX_OFF  = (long)NPTS * RVQ_D;        // 8388608
static constexpr long LOSS_OFF = IDX_OFF + (long)NPTS * RVQ_Q;
static constexpr int  NWAVES   = 1024;                      // 1 per SIMD
static constexpr int  PPW      = NPTS / NWAVES;             // 256 points/wave

__device__ __forceinline__ float f4e(const float4& v, int c) {
    return c == 0 ? v.x : c == 1 ? v.y : c == 2 ? v.z : v.w;
}

// ---------------------------------------------------------------------------
// Kernel 1: per-codeword squared norms -> ws[Q*C] (bit-exact numpy tree)
__global__ void rvq_cb_norms(const float* __restrict__ cb, float* __restrict__ ws) {
    int i = blockIdx.x * blockDim.x + threadIdx.x;
    if (i >= RVQ_Q * RVQ_C) return;
    const float* c = cb + (long)i * RVQ_D;
    float a[8];
#pragma unroll
    for (int j = 0; j < 8; ++j) a[j] = c[j] * c[j];
#pragma unroll
    for (int j = 8; j < RVQ_D; ++j) a[j & 7] = fmaf(c[j], c[j], a[j & 7]);
    ws[i] = ((a[0] + a[1]) + (a[2] + a[3])) + ((a[4] + a[5]) + (a[6] + a[7]));
}

// ---------------------------------------------------------------------------
// Kernel 2: one VQ stage. Block = 64 (one wave). Each lane owns candidates
// [lane*8, lane*8+8). rin = residual in (z for q==0), rout = residual out.
__global__ __launch_bounds__(64, 1) void rvq_stage(const float* __restrict__ rin,
                                                   float* __restrict__ rout,
                                                   const float* __restrict__ cb,
                                                   const float* __restrict__ cbn,
                                                   float* __restrict__ idx_out,
                                                   int q) {
    const int  lane  = threadIdx.x;          // 0..63 (block == 1 wave)
    const long pbase = (long)blockIdx.x * PPW;

    // ---- codebook slice into registers: 8 codewords/lane, static indexing
    float4 cw[8][8];
    {
        const float4* cbase = (const float4*)(cb + ((long)q * RVQ_C + lane * 8) * RVQ_D);
#pragma unroll
        for (int j = 0; j < 8; ++j)
#pragma unroll
            for (int w = 0; w < 8; ++w) cw[j][w] = cbase[j * 8 + w];
    }
    float cc[8];
#pragma unroll
    for (int j = 0; j < 8; ++j) cc[j] = cbn[q * RVQ_C + lane * 8 + j];

    const float4* rin4 = (const float4*)rin;

    // distance+argmin for one point given its residual (same values in all
    // lanes). Bit-identical tree to R1: 8-acc j&7 dot, fma(-2,dot,rr)+cc,
    // ascending-index strict-< scan, butterfly with lower-idx tie-break.
    auto process = [&](const float4 (&rb4)[8]) -> int {
        float rb[RVQ_D];
#pragma unroll
        for (int w = 0; w < 8; ++w) {
            rb[w * 4 + 0] = rb4[w].x; rb[w * 4 + 1] = rb4[w].y;
            rb[w * 4 + 2] = rb4[w].z; rb[w * 4 + 3] = rb4[w].w;
        }
        float a[8];
#pragma unroll
        for (int j = 0; j < 8; ++j) a[j] = rb[j] * rb[j];
#pragma unroll
        for (int j = 8; j < RVQ_D; ++j) a[j & 7] = fmaf(rb[j], rb[j], a[j & 7]);
        const float rr = ((a[0] + a[1]) + (a[2] + a[3])) + ((a[4] + a[5]) + (a[6] + a[7]));

        float bd = __builtin_inff();
        int   bj = 0;
#pragma unroll
        for (int j = 0; j < 8; ++j) {
            float acc[8];
#pragma unroll
            for (int d = 0; d < 8; ++d) acc[d] = rb[d] * f4e(cw[j][d >> 2], d & 3);
#pragma unroll
            for (int d = 8; d < RVQ_D; ++d)
                acc[d & 7] = fmaf(rb[d], f4e(cw[j][d >> 2], d & 3), acc[d & 7]);
            const float dot = ((acc[0] + acc[1]) + (acc[2] + acc[3])) +
                              ((acc[4] + acc[5]) + (acc[6] + acc[7]));
            const float dist = fmaf(-2.0f, dot, rr) + cc[j];
            if (dist < bd) { bd = dist; bj = j; }   // first-min within lane
        }
        int bi = lane * 8 + bj;
#pragma unroll
        for (int m = 1; m <= 32; m <<= 1) {
            const float od = __shfl_xor(bd, m, 64);
            const int   oi = __shfl_xor(bi, m, 64);
            if (od < bd || (od == bd && oi < bi)) { bd = od; bi = oi; }
        }
        return bi;   // uniform across the wave
    };

    const int dlane = lane & 31;
    // finish a deferred residual update: bit-exact reference chain
    auto finish = [&](long p, float rl, float cwl) {
        const float t   = cwl - rl;
        const float qst = rl + t;
        const float rn  = rl - qst;
        if (lane < 32) rout[p * RVQ_D + lane] = rn;
    };

    float4 rbA[8], rbB[8];
#pragma unroll
    for (int w = 0; w < 8; ++w) rbA[w] = rin4[pbase * 8 + w];

    long  pPend = 0; float rlPend = 0.0f, cwPend = 0.0f;

#pragma unroll 1
    for (int i = 0; i < PPW; i += 2) {
        const long p0 = pbase + i, p1 = p0 + 1;

        // prefetch residual of p1 (covers its load latency under p0 compute)
#pragma unroll
        for (int w = 0; w < 8; ++w) rbB[w] = rin4[p1 * 8 + w];

        const int bi0 = process(rbA);
        if (lane == 0) idx_out[p0 * RVQ_Q + q] = (float)bi0;
        // issue update loads for p0 (finish after next point's compute)
        const float rl0 = rin[p0 * RVQ_D + dlane];
        const float cw0 = cb[((long)q * RVQ_C + bi0) * RVQ_D + dlane];
        if (i > 0) finish(pPend, rlPend, cwPend);

        // prefetch residual of p0+2
        if (i + 2 < PPW) {
#pragma unroll
            for (int w = 0; w < 8; ++w) rbA[w] = rin4[(p0 + 2) * 8 + w];
        }

        const int bi1 = process(rbB);
        if (lane == 0) idx_out[p1 * RVQ_Q + q] = (float)bi1;
        const float rl1 = rin[p1 * RVQ_D + dlane];
        const float cw1 = cb[((long)q * RVQ_C + bi1) * RVQ_D + dlane];
        finish(p0, rl0, cw0);

        pPend = p1; rlPend = rl1; cwPend = cw1;
    }
    finish(pPend, rlPend, cwPend);
}

// ---------------------------------------------------------------------------
// Kernel 3: replay the straight-through chain from stored indices; writes
// quantized + commit_loss. Bit-identical op order to the reference. (R3-proven)
__global__ __launch_bounds__(256) void rvq_replay(const float* __restrict__ z,
                                                  const float* __restrict__ cb,
                                                  float* __restrict__ out) {
    const int p = blockIdx.x * 256 + threadIdx.x;

    float r[RVQ_D], oacc[RVQ_D];
    {
        const float4* zp = (const float4*)(z + (long)p * RVQ_D);
#pragma unroll
        for (int w = 0; w < 8; ++w) {
            const float4 v = zp[w];
            r[w * 4 + 0] = v.x; r[w * 4 + 1] = v.y;
            r[w * 4 + 2] = v.z; r[w * 4 + 3] = v.w;
        }
    }
#pragma unroll
    for (int d = 0; d < RVQ_D; ++d) oacc[d] = 0.0f;

#pragma unroll 1
    for (int q = 0; q < RVQ_Q; ++q) {
        const int idx = (int)out[IDX_OFF + (long)p * RVQ_Q + q];
        const float4* cwb = (const float4*)(cb + ((long)q * RVQ_C + idx) * RVQ_D);
        float cwv[RVQ_D];
#pragma unroll
        for (int w = 0; w < 8; ++w) {
            const float4 v = cwb[w];
            cwv[w * 4 + 0] = v.x; cwv[w * 4 + 1] = v.y;
            cwv[w * 4 + 2] = v.z; cwv[w * 4 + 3] = v.w;
        }
#pragma unroll
        for (int d = 0; d < RVQ_D; ++d) {
            const float qst = r[d] + (cwv[d] - r[d]);
            oacc[d] += qst;
            r[d] = r[d] - qst;
        }
    }

    float4* qo = (float4*)(out + (long)p * RVQ_D);
#pragma unroll
    for (int w = 0; w < 8; ++w) {
        float4 v;
        v.x = oacc[w * 4 + 0]; v.y = oacc[w * 4 + 1];
        v.z = oacc[w * 4 + 2]; v.w = oacc[w * 4 + 3];
        qo[w] = v;
    }

    if (p < RVQ_Q) out[LOSS_OFF + p] = 0.0f;
}

// ---------------------------------------------------------------------------
extern "C" void kernel_launch(void* const* d_in, const int* in_sizes, int n_in,
                              void* d_out, int out_size, void* d_ws, size_t ws_size,
                              hipStream_t stream) {
    const float* z  = (const float*)d_in[0];
    const float* cb = (const float*)d_in[1];
    float* out  = (float*)d_out;
    float* cbn  = (float*)d_ws;          // Q*C floats = 20 KiB scratch
    float* rbuf = out;                   // residual lives in quantized region;
                                         // replay overwrites it at the end
    float* iout = out + IDX_OFF;

    rvq_cb_norms<<<(RVQ_Q * RVQ_C + 255) / 256, 256, 0, stream>>>(cb, cbn);
    for (int q = 0; q < RVQ_Q; ++q)
        rvq_stage<<<NWAVES, 64, 0, stream>>>(q == 0 ? z : rbuf, rbuf, cb, cbn, iout, q);
    rvq_replay<<<NPTS / 256, 256, 0, stream>>>(z, cb, out);
}